// Round 2
// baseline (215.789 us; speedup 1.0000x reference)
//
#include <hip/hip_runtime.h>
#include <hip/hip_bf16.h>

#define DIM 4096
#define HD 128
#define NQH 32
#define NKVH 8
#define NB 8
#define MAXSEQ 4096
#define TOTALT 4096          // start_pos + 1 = 4096 (start_pos fixed at 4095)
#define QCOLS (NQH*HD)       // 4096
#define KVCOLS (NKVH*HD)     // 1024
#define CCOLS (QCOLS + 2*KVCOLS) // 6144
#define DCHUNK 128
#define KSPLIT (DIM/DCHUNK)  // 32
#define TCHUNK 256
#define NCHUNK (TOTALT/TCHUNK) // 16

// ---------------------------------------------------------------------------
// Split-K GEMV partials: out[b][col] partial over d-range [ky*DCHUNK, +DCHUNK)
// thread = one column; lanes cover consecutive columns -> coalesced w reads.
// x chunk (8 x 128) staged in LDS, broadcast-read.
// ---------------------------------------------------------------------------
__global__ __launch_bounds__(256) void gemv_part_kernel(
    const float* __restrict__ x, const float* __restrict__ w,
    float* __restrict__ part, int wcols, int pstride, int colofs)
{
    __shared__ float xs[NB*DCHUNK];
    const int tx = threadIdx.x;
    const int col = blockIdx.x*256 + tx;
    const int d0 = blockIdx.y*DCHUNK;

    for (int i = tx; i < NB*DCHUNK; i += 256)
        xs[i] = x[(i>>7)*DIM + d0 + (i&127)];
    __syncthreads();

    float acc[NB];
    #pragma unroll
    for (int b = 0; b < NB; b++) acc[b] = 0.f;

    const float* wp = w + (size_t)d0*wcols + col;
    #pragma unroll 4
    for (int dl = 0; dl < DCHUNK; dl += 4) {
        float4 xv[NB];
        #pragma unroll
        for (int b = 0; b < NB; b++)
            xv[b] = *reinterpret_cast<const float4*>(&xs[b*DCHUNK + dl]);
        #pragma unroll
        for (int jj = 0; jj < 4; jj++) {
            float wv = wp[(size_t)(dl + jj)*wcols];
            #pragma unroll
            for (int b = 0; b < NB; b++) {
                float xb = (jj==0)?xv[b].x:(jj==1)?xv[b].y:(jj==2)?xv[b].z:xv[b].w;
                acc[b] += wv * xb;
            }
        }
    }
    const int ky = blockIdx.y;
    #pragma unroll
    for (int b = 0; b < NB; b++)
        part[((size_t)ky*NB + b)*pstride + colofs + col] = acc[b];
}

// ---------------------------------------------------------------------------
// Reduce QKV split-K partials + apply RoPE to q,k. One thread per (even,odd)
// column pair.
// ---------------------------------------------------------------------------
__global__ __launch_bounds__(256) void qkv_reduce_rope(
    const float* __restrict__ part, const float* __restrict__ fc,
    const float* __restrict__ fs, float* __restrict__ q,
    float* __restrict__ knew, float* __restrict__ vnew)
{
    const int p = blockIdx.x*256 + threadIdx.x;   // 0 .. NB*CCOLS/2-1
    const int b = p / (CCOLS/2);
    const int c0 = (p % (CCOLS/2))*2;
    float s0 = 0.f, s1 = 0.f;
    const float* pb = part + (size_t)b*CCOLS + c0;
    #pragma unroll
    for (int ky = 0; ky < KSPLIT; ky++) {
        s0 += pb[(size_t)ky*NB*CCOLS];
        s1 += pb[(size_t)ky*NB*CCOLS + 1];
    }
    float r0 = s0, r1 = s1;
    if (c0 < QCOLS + KVCOLS) {           // q or k: apply rope
        int i = (c0 & (HD-1)) >> 1;
        float c = fc[i], s = fs[i];
        r0 = s0*c - s1*s;
        r1 = s0*s + s1*c;
    }
    if (c0 < QCOLS) {
        q[b*QCOLS + c0] = r0; q[b*QCOLS + c0 + 1] = r1;
    } else if (c0 < QCOLS + KVCOLS) {
        int cc = c0 - QCOLS;
        knew[b*KVCOLS + cc] = r0; knew[b*KVCOLS + cc + 1] = r1;
    } else {
        int cc = c0 - QCOLS - KVCOLS;
        vnew[b*KVCOLS + cc] = r0; vnew[b*KVCOLS + cc + 1] = r1;
    }
}

// ---------------------------------------------------------------------------
// Flash-decode partials. Block = (t-chunk of 256, kvh, b). 256 threads.
// Phase 1: thread t -> scores of 4 q-heads vs K[t]. Position 4095 uses knew.
// Phase 2: wave j -> partial softmax (m, l, p) for head j.
// Phase 3: thread (j, d-pair) -> partial out[j][d] = sum_t p * V[t][d].
// ---------------------------------------------------------------------------
__global__ __launch_bounds__(256) void attn_part_kernel(
    const float* __restrict__ q, const float* __restrict__ knew,
    const float* __restrict__ vnew, const float* __restrict__ K,
    const float* __restrict__ V, float* __restrict__ pout,
    float* __restrict__ pml)
{
    __shared__ float qs[4*HD];
    __shared__ float ps[TCHUNK*4];
    const int tx = threadIdx.x;
    const int chunk = blockIdx.x, kvh = blockIdx.y, b = blockIdx.z;
    const int tbase = chunk*TCHUNK;
    const size_t blkid = (size_t)(b*NKVH + kvh)*NCHUNK + chunk;

    for (int i = tx; i < 4*HD; i += 256)
        qs[i] = q[b*QCOLS + kvh*4*HD + i];
    __syncthreads();

    // phase 1: scores
    {
        const int t = tbase + tx;
        const float* krow = (t == TOTALT-1)
            ? (knew + (b*NKVH + kvh)*HD)
            : (K + ((size_t)(b*MAXSEQ + t)*NKVH + kvh)*HD);
        const float4* k4 = reinterpret_cast<const float4*>(krow);
        const float4* q4 = reinterpret_cast<const float4*>(qs);
        float sj[4] = {0.f, 0.f, 0.f, 0.f};
        #pragma unroll 8
        for (int i = 0; i < HD/4; i++) {
            float4 kv = k4[i];
            #pragma unroll
            for (int j = 0; j < 4; j++) {
                float4 qv = q4[j*(HD/4) + i];
                sj[j] += kv.x*qv.x + kv.y*qv.y + kv.z*qv.z + kv.w*qv.w;
            }
        }
        const float scale = 0.08838834764831845f;  // 1/sqrt(128)
        float4 sv;
        sv.x = sj[0]*scale; sv.y = sj[1]*scale;
        sv.z = sj[2]*scale; sv.w = sj[3]*scale;
        *reinterpret_cast<float4*>(&ps[tx*4]) = sv;
    }
    __syncthreads();

    // phase 2: per-head partial softmax (wave j handles head j)
    {
        const int j = tx >> 6;
        const int lane = tx & 63;
        float v0 = ps[(lane      )*4 + j];
        float v1 = ps[(lane +  64)*4 + j];
        float v2 = ps[(lane + 128)*4 + j];
        float v3 = ps[(lane + 192)*4 + j];
        float m = fmaxf(fmaxf(v0, v1), fmaxf(v2, v3));
        #pragma unroll
        for (int k = 32; k >= 1; k >>= 1) m = fmaxf(m, __shfl_xor(m, k, 64));
        float p0 = __expf(v0 - m), p1 = __expf(v1 - m);
        float p2 = __expf(v2 - m), p3 = __expf(v3 - m);
        float l = p0 + p1 + p2 + p3;
        #pragma unroll
        for (int k = 32; k >= 1; k >>= 1) l += __shfl_xor(l, k, 64);
        ps[(lane      )*4 + j] = p0;
        ps[(lane +  64)*4 + j] = p1;
        ps[(lane + 128)*4 + j] = p2;
        ps[(lane + 192)*4 + j] = p3;
        if (lane == 0) {
            pml[blkid*8 + j] = m;
            pml[blkid*8 + 4 + j] = l;
        }
    }
    __syncthreads();

    // phase 3: V accumulation. wave j handles head j, lanes cover d (coalesced)
    {
        const int j = tx >> 6;
        const int d0 = (tx & 63)*2;
        const float* vbase = V + ((size_t)(b*MAXSEQ + tbase)*NKVH + kvh)*HD + d0;
        float a0 = 0.f, a1 = 0.f;
        const int nmain = (tbase + TCHUNK >= TOTALT) ? TCHUNK-1 : TCHUNK;
        for (int tt = 0; tt < nmain; tt++) {
            float p = ps[tt*4 + j];
            const float2 vv = *reinterpret_cast<const float2*>(vbase + (size_t)tt*NKVH*HD);
            a0 += p*vv.x; a1 += p*vv.y;
        }
        if (nmain != TCHUNK) {   // position 4095 -> new v
            float p = ps[(TCHUNK-1)*4 + j];
            const float2 vv = *reinterpret_cast<const float2*>(vnew + (b*NKVH + kvh)*HD + d0);
            a0 += p*vv.x; a1 += p*vv.y;
        }
        float* po = pout + blkid*512 + j*HD + d0;
        po[0] = a0; po[1] = a1;
    }
}

// ---------------------------------------------------------------------------
// Log-sum-exp combine across the 16 t-chunks. Block = (qh, b), 128 threads (d).
// ---------------------------------------------------------------------------
__global__ __launch_bounds__(128) void attn_combine_kernel(
    const float* __restrict__ pout, const float* __restrict__ pml,
    float* __restrict__ attn_out)
{
    const int d = threadIdx.x;
    const int qh = blockIdx.x;
    const int b = blockIdx.y;
    const int kvh = qh >> 2, j = qh & 3;
    const size_t base = (size_t)(b*NKVH + kvh)*NCHUNK;
    float mv[NCHUNK];
    float M = -1e30f;
    #pragma unroll
    for (int i = 0; i < NCHUNK; i++) {
        mv[i] = pml[(base + i)*8 + j];
        M = fmaxf(M, mv[i]);
    }
    float L = 0.f, acc = 0.f;
    #pragma unroll
    for (int i = 0; i < NCHUNK; i++) {
        float wgt = __expf(mv[i] - M);
        L   += wgt * pml[(base + i)*8 + 4 + j];
        acc += wgt * pout[(base + i)*512 + j*HD + d];
    }
    attn_out[b*QCOLS + qh*HD + d] = acc / L;
}

// ---------------------------------------------------------------------------
// Final split-K reduce for wo, writes f32 output (reference output is float32).
// ---------------------------------------------------------------------------
__global__ __launch_bounds__(256) void wo_reduce_kernel(
    const float* __restrict__ part, float* __restrict__ out)
{
    const int idx = blockIdx.x*256 + threadIdx.x;   // 0..32767
    float s = 0.f;
    #pragma unroll
    for (int ky = 0; ky < KSPLIT; ky++)
        s += part[(size_t)ky*(NB*QCOLS) + idx];
    out[idx] = s;
}

extern "C" void kernel_launch(void* const* d_in, const int* in_sizes, int n_in,
                              void* d_out, int out_size, void* d_ws, size_t ws_size,
                              hipStream_t stream)
{
    const float* x  = (const float*)d_in[0];
    // d_in[1] = start_pos (int scalar) = 4095, fixed by the problem.
    const float* fc = (const float*)d_in[2];
    const float* fs = (const float*)d_in[3];
    const float* wq = (const float*)d_in[4];
    const float* wk = (const float*)d_in[5];
    const float* wv = (const float*)d_in[6];
    const float* wo = (const float*)d_in[7];
    const float* K  = (const float*)d_in[8];
    const float* V  = (const float*)d_in[9];

    float* ws     = (float*)d_ws;
    float* q      = ws;                 // 32768
    float* knew   = ws + 32768;         // 8192
    float* vnew   = ws + 40960;         // 8192
    float* attn_o = ws + 49152;         // 32768
    float* qkvp   = ws + 81920;         // 32*8*6144 = 1572864
    float* pout   = ws + 1654784;       // 1024*512  = 524288
    float* pml    = ws + 2179072;       // 1024*8    = 8192
    float* wop    = ws + 2187264;       // 32*8*4096 = 1048576  (end 3235840 floats ~12.9MB)

    // QKV projection partials (split-K over d)
    gemv_part_kernel<<<dim3(QCOLS/256,  KSPLIT), dim3(256), 0, stream>>>(x, wq, qkvp, QCOLS,  CCOLS, 0);
    gemv_part_kernel<<<dim3(KVCOLS/256, KSPLIT), dim3(256), 0, stream>>>(x, wk, qkvp, KVCOLS, CCOLS, QCOLS);
    gemv_part_kernel<<<dim3(KVCOLS/256, KSPLIT), dim3(256), 0, stream>>>(x, wv, qkvp, KVCOLS, CCOLS, QCOLS + KVCOLS);
    // reduce + RoPE
    qkv_reduce_rope<<<dim3(NB*CCOLS/2/256), dim3(256), 0, stream>>>(qkvp, fc, fs, q, knew, vnew);
    // flash-decode partials + combine
    attn_part_kernel<<<dim3(NCHUNK, NKVH, NB), dim3(256), 0, stream>>>(q, knew, vnew, K, V, pout, pml);
    attn_combine_kernel<<<dim3(NQH, NB), dim3(128), 0, stream>>>(pout, pml, attn_o);
    // output projection
    gemv_part_kernel<<<dim3(QCOLS/256, KSPLIT), dim3(256), 0, stream>>>(attn_o, wo, wop, QCOLS, QCOLS, 0);
    wo_reduce_kernel<<<dim3(NB*QCOLS/256), dim3(256), 0, stream>>>(wop, (float*)d_out);
}

// Round 3
// 151.336 us; speedup vs baseline: 1.4259x; 1.4259x over previous
//
#include <hip/hip_runtime.h>

#define DIM 4096
#define HD 128
#define NQH 32
#define NKVH 8
#define NB 8
#define MAXSEQ 4096
#define TOTALT 4096          // start_pos + 1 (start_pos fixed 4095)
#define QCOLS (NQH*HD)       // 4096
#define KVCOLS (NKVH*HD)     // 1024
#define CCOLS (QCOLS + 2*KVCOLS) // 6144
#define DCH 64               // split-K d-chunk
#define KSP (DIM/DCH)        // 64
#define TCH 64               // attention t-chunk
#define NCH (TOTALT/TCH)     // 64

// ---------------------------------------------------------------------------
// Fused GEMV partials, thread = 4 consecutive columns (float4 weight loads).
// grid = (col_blocks, KSP). Column range picks wq/wk/wv (1024-aligned splits).
// For the wo projection, pass wq=wk=wv=wo (colbase<4096 always hits branch 1).
// x staged transposed in LDS: xs[d][b] -> inner loop = 2 b128 broadcasts.
// ---------------------------------------------------------------------------
__global__ __launch_bounds__(256) void gemv4_kernel(
    const float* __restrict__ x, const float* __restrict__ wq,
    const float* __restrict__ wk, const float* __restrict__ wv,
    float* __restrict__ part, int pstride)
{
    __shared__ float xs[DCH*NB];       // [d][b]
    const int tx = threadIdx.x;
    const int d0 = blockIdx.y*DCH;
    {
        int i0 = tx, i1 = tx + 256;    // i = b*64 + d
        xs[(i0&63)*NB + (i0>>6)] = x[(i0>>6)*DIM + d0 + (i0&63)];
        xs[(i1&63)*NB + (i1>>6)] = x[(i1>>6)*DIM + d0 + (i1&63)];
    }
    __syncthreads();

    const int colbase = blockIdx.x*1024;
    const float* w; int wcols, wcol;
    if (colbase < QCOLS)               { w = wq; wcols = QCOLS;  wcol = colbase; }
    else if (colbase < QCOLS+KVCOLS)   { w = wk; wcols = KVCOLS; wcol = colbase - QCOLS; }
    else                               { w = wv; wcols = KVCOLS; wcol = colbase - QCOLS - KVCOLS; }

    const float* wp = w + (size_t)d0*wcols + wcol + tx*4;
    float4 a[NB];
    #pragma unroll
    for (int b = 0; b < NB; b++) { a[b].x=0.f; a[b].y=0.f; a[b].z=0.f; a[b].w=0.f; }

    #pragma unroll 4
    for (int dl = 0; dl < DCH; dl++) {
        float4 wv4 = *reinterpret_cast<const float4*>(wp + (size_t)dl*wcols);
        float4 x0 = *reinterpret_cast<const float4*>(&xs[dl*NB]);
        float4 x1 = *reinterpret_cast<const float4*>(&xs[dl*NB + 4]);
        a[0].x += wv4.x*x0.x; a[0].y += wv4.y*x0.x; a[0].z += wv4.z*x0.x; a[0].w += wv4.w*x0.x;
        a[1].x += wv4.x*x0.y; a[1].y += wv4.y*x0.y; a[1].z += wv4.z*x0.y; a[1].w += wv4.w*x0.y;
        a[2].x += wv4.x*x0.z; a[2].y += wv4.y*x0.z; a[2].z += wv4.z*x0.z; a[2].w += wv4.w*x0.z;
        a[3].x += wv4.x*x0.w; a[3].y += wv4.y*x0.w; a[3].z += wv4.z*x0.w; a[3].w += wv4.w*x0.w;
        a[4].x += wv4.x*x1.x; a[4].y += wv4.y*x1.x; a[4].z += wv4.z*x1.x; a[4].w += wv4.w*x1.x;
        a[5].x += wv4.x*x1.y; a[5].y += wv4.y*x1.y; a[5].z += wv4.z*x1.y; a[5].w += wv4.w*x1.y;
        a[6].x += wv4.x*x1.z; a[6].y += wv4.y*x1.z; a[6].z += wv4.z*x1.z; a[6].w += wv4.w*x1.z;
        a[7].x += wv4.x*x1.w; a[7].y += wv4.y*x1.w; a[7].z += wv4.z*x1.w; a[7].w += wv4.w*x1.w;
    }
    const int ocol = colbase + tx*4;
    #pragma unroll
    for (int b = 0; b < NB; b++)
        *reinterpret_cast<float4*>(&part[((size_t)(blockIdx.y*NB + b))*pstride + ocol]) = a[b];
}

// ---------------------------------------------------------------------------
// Reduce QKV split-K partials (float2) + RoPE on q,k.
// ---------------------------------------------------------------------------
__global__ __launch_bounds__(256) void qkv_reduce_rope(
    const float* __restrict__ part, const float* __restrict__ fc,
    const float* __restrict__ fs, float* __restrict__ q,
    float* __restrict__ knew, float* __restrict__ vnew)
{
    const int p = blockIdx.x*256 + threadIdx.x;   // 0 .. NB*CCOLS/2-1
    const int b = p / (CCOLS/2);
    const int c0 = (p % (CCOLS/2))*2;
    float s0 = 0.f, s1 = 0.f;
    const float* pb = part + (size_t)b*CCOLS + c0;
    #pragma unroll 8
    for (int ky = 0; ky < KSP; ky++) {
        float2 v = *reinterpret_cast<const float2*>(pb + (size_t)ky*NB*CCOLS);
        s0 += v.x; s1 += v.y;
    }
    float r0 = s0, r1 = s1;
    if (c0 < QCOLS + KVCOLS) {           // q or k: rope
        int i = (c0 & (HD-1)) >> 1;
        float c = fc[i], s = fs[i];
        r0 = s0*c - s1*s;
        r1 = s0*s + s1*c;
    }
    if (c0 < QCOLS) {
        *reinterpret_cast<float2*>(&q[b*QCOLS + c0]) = make_float2(r0, r1);
    } else if (c0 < QCOLS + KVCOLS) {
        *reinterpret_cast<float2*>(&knew[b*KVCOLS + (c0 - QCOLS)]) = make_float2(r0, r1);
    } else {
        *reinterpret_cast<float2*>(&vnew[b*KVCOLS + (c0 - QCOLS - KVCOLS)]) = make_float2(r0, r1);
    }
}

// ---------------------------------------------------------------------------
// Flash-decode partial, TCH=64. Block = (chunk, kvh, b), 256 threads.
// K staged in LDS via coalesced loads, XOR-swizzled float4 layout
// (stored chunk index s = c ^ (t&31)): both ds_write and ds_read hit the
// 8 words/bank structural minimum (zero excess conflicts).
// Scores: lane t of wave j holds score(head j, row t); softmax partial via
// 64-lane register butterfly. PV: lanes across d, coalesced V rows.
// ---------------------------------------------------------------------------
__global__ __launch_bounds__(256) void attn_part_kernel(
    const float* __restrict__ q, const float* __restrict__ knew,
    const float* __restrict__ vnew, const float* __restrict__ K,
    const float* __restrict__ V, float* __restrict__ pout,
    float* __restrict__ pml)
{
    __shared__ float ks[TCH*HD];   // 32 KB, swizzled
    __shared__ float qs[4*HD];     // 2 KB
    __shared__ float ps[4*TCH];    // 1 KB
    const int tx = threadIdx.x;
    const int chunk = blockIdx.x, kvh = blockIdx.y, b = blockIdx.z;
    const int tbase = chunk*TCH;
    const size_t blkid = (size_t)(b*NKVH + kvh)*NCH + chunk;

    {   // q: 512 floats
        int i0 = tx, i1 = tx + 256;
        qs[i0] = q[b*QCOLS + kvh*4*HD + i0];
        qs[i1] = q[b*QCOLS + kvh*4*HD + i1];
    }
    // K staging: 2048 float4s, 8 per thread, coalesced global reads
    const size_t kbase = ((size_t)(b*MAXSEQ + tbase)*NKVH + kvh)*HD;
    #pragma unroll
    for (int k = 0; k < 8; k++) {
        int F = tx + k*256;            // float4 index
        int t = F >> 5, i = F & 31;
        const float4* src;
        if (chunk == NCH-1 && t == TCH-1)
            src = reinterpret_cast<const float4*>(knew + (b*NKVH + kvh)*HD) + i;
        else
            src = reinterpret_cast<const float4*>(K + kbase + (size_t)t*NKVH*HD) + i;
        float4 v = *src;
        int s = i ^ (t & 31);
        *reinterpret_cast<float4*>(&ks[(t*32 + s)*4]) = v;
    }
    __syncthreads();

    const int t = tx & 63, j = tx >> 6;
    // phase 1: score(j, t)
    float sj = 0.f;
    {
        const float4* q4 = reinterpret_cast<const float4*>(&qs[j*HD]);
        #pragma unroll 8
        for (int c = 0; c < 32; c++) {
            int s = c ^ (t & 31);
            float4 kv = *reinterpret_cast<const float4*>(&ks[(t*32 + s)*4]);
            float4 qv = q4[c];
            sj += kv.x*qv.x + kv.y*qv.y + kv.z*qv.z + kv.w*qv.w;
        }
        sj *= 0.08838834764831845f;   // 1/sqrt(128)
    }
    // phase 2: wave-level softmax partial (registers only)
    float m = sj;
    #pragma unroll
    for (int k = 32; k >= 1; k >>= 1) m = fmaxf(m, __shfl_xor(m, k, 64));
    float pw = __expf(sj - m);
    float l = pw;
    #pragma unroll
    for (int k = 32; k >= 1; k >>= 1) l += __shfl_xor(l, k, 64);
    ps[j*TCH + t] = pw;
    if (t == 0) {
        pml[blkid*8 + j] = m;
        pml[blkid*8 + 4 + j] = l;
    }
    __syncthreads();

    // phase 3: PV. wave j, lanes across d (float2), coalesced V rows.
    const int d0 = (tx & 63)*2;
    const float* vbase = V + ((size_t)(b*MAXSEQ + tbase)*NKVH + kvh)*HD + d0;
    float a0 = 0.f, a1 = 0.f;
    const int nmain = (chunk == NCH-1) ? TCH-1 : TCH;
    #pragma unroll 4
    for (int tt = 0; tt < nmain; tt++) {
        float p = ps[j*TCH + tt];
        float2 vv = *reinterpret_cast<const float2*>(vbase + (size_t)tt*NKVH*HD);
        a0 += p*vv.x; a1 += p*vv.y;
    }
    if (nmain != TCH) {    // row 4095 -> new v
        float p = ps[j*TCH + TCH-1];
        float2 vv = *reinterpret_cast<const float2*>(vnew + (b*NKVH + kvh)*HD + d0);
        a0 += p*vv.x; a1 += p*vv.y;
    }
    *reinterpret_cast<float2*>(pout + blkid*512 + j*HD + d0) = make_float2(a0, a1);
}

// ---------------------------------------------------------------------------
// LSE combine across NCH chunks. Block = (qh, b), 128 threads (d).
// Two passes over pml (L2-resident) to avoid a 64-register array.
// ---------------------------------------------------------------------------
__global__ __launch_bounds__(128) void attn_combine_kernel(
    const float* __restrict__ pout, const float* __restrict__ pml,
    float* __restrict__ attn_out)
{
    const int d = threadIdx.x;
    const int qh = blockIdx.x;
    const int b = blockIdx.y;
    const int kvh = qh >> 2, j = qh & 3;
    const size_t base = (size_t)(b*NKVH + kvh)*NCH;
    float M = -1e30f;
    for (int i = 0; i < NCH; i++)
        M = fmaxf(M, pml[(base + i)*8 + j]);
    float L = 0.f, acc = 0.f;
    for (int i = 0; i < NCH; i++) {
        float mi = pml[(base + i)*8 + j];
        float wgt = __expf(mi - M);
        L   += wgt * pml[(base + i)*8 + 4 + j];
        acc += wgt * pout[(base + i)*512 + j*HD + d];
    }
    attn_out[b*QCOLS + qh*HD + d] = acc / L;
}

// ---------------------------------------------------------------------------
// Final split-K reduce for wo (float2), f32 output.
// ---------------------------------------------------------------------------
__global__ __launch_bounds__(256) void wo_reduce_kernel(
    const float* __restrict__ part, float* __restrict__ out)
{
    const int g = blockIdx.x*256 + threadIdx.x;   // float2 index, 0..16383
    float sx = 0.f, sy = 0.f;
    #pragma unroll 8
    for (int ky = 0; ky < KSP; ky++) {
        float2 v = *reinterpret_cast<const float2*>(part + (size_t)ky*NB*QCOLS + g*2);
        sx += v.x; sy += v.y;
    }
    *reinterpret_cast<float2*>(out + g*2) = make_float2(sx, sy);
}

extern "C" void kernel_launch(void* const* d_in, const int* in_sizes, int n_in,
                              void* d_out, int out_size, void* d_ws, size_t ws_size,
                              hipStream_t stream)
{
    const float* x  = (const float*)d_in[0];
    // d_in[1] = start_pos (int scalar) = 4095, fixed by the problem.
    const float* fc = (const float*)d_in[2];
    const float* fs = (const float*)d_in[3];
    const float* wq = (const float*)d_in[4];
    const float* wk = (const float*)d_in[5];
    const float* wv = (const float*)d_in[6];
    const float* wo = (const float*)d_in[7];
    const float* K  = (const float*)d_in[8];
    const float* V  = (const float*)d_in[9];

    float* ws     = (float*)d_ws;
    float* q      = ws;                 // 32768
    float* knew   = ws + 32768;         // 8192
    float* vnew   = ws + 40960;         // 8192
    float* attn_o = ws + 49152;         // 32768
    float* A      = ws + 81920;         // shared region, 3,145,728 floats
    // region A time-shared:
    float* qkvp = A;                    // 64*8*6144 = 3,145,728   (k1..k2)
    float* pout = A;                    // 4096*512  = 2,097,152   (k3..k4)
    float* pml  = A + 2097152;          // 4096*8    = 32,768      (k3..k4)
    float* wop  = A;                    // 64*8*4096 = 2,097,152   (k5..k6)
    // total ws use: 81920 + 3,145,728 floats = 12.9 MB

    // 1. fused QKV projection partials
    gemv4_kernel<<<dim3(CCOLS/1024, KSP), dim3(256), 0, stream>>>(x, wq, wk, wv, qkvp, CCOLS);
    // 2. reduce + RoPE
    qkv_reduce_rope<<<dim3(NB*CCOLS/2/256), dim3(256), 0, stream>>>(qkvp, fc, fs, q, knew, vnew);
    // 3. flash-decode partials
    attn_part_kernel<<<dim3(NCH, NKVH, NB), dim3(256), 0, stream>>>(q, knew, vnew, K, V, pout, pml);
    // 4. LSE combine
    attn_combine_kernel<<<dim3(NQH, NB), dim3(128), 0, stream>>>(pout, pml, attn_o);
    // 5. output projection partials (reuses gemv4: colbase<4096 -> first w)
    gemv4_kernel<<<dim3(QCOLS/1024, KSP), dim3(256), 0, stream>>>(attn_o, wo, wo, wo, wop, QCOLS);
    // 6. final reduce, f32 out
    wo_reduce_kernel<<<dim3(NB*QCOLS/2/256), dim3(256), 0, stream>>>(wop, (float*)d_out);
}

// Round 4
// 132.774 us; speedup vs baseline: 1.6252x; 1.1398x over previous
//
#include <hip/hip_runtime.h>

#define DIM 4096
#define HD 128
#define NQH 32
#define NKVH 8
#define NB 8
#define MAXSEQ 4096
#define TOTALT 4096          // start_pos + 1 (start_pos fixed 4095)
#define QCOLS (NQH*HD)       // 4096
#define KVCOLS (NKVH*HD)     // 1024
#define CCOLS (QCOLS + 2*KVCOLS) // 6144
#define DCH 64               // split-K d-chunk
#define KSP (DIM/DCH)        // 64
#define TCH 64               // attention t-chunk
#define NCH (TOTALT/TCH)     // 64

// ---------------------------------------------------------------------------
// Fused GEMV partials. 128 threads, 512 cols/block (4/thread, float4 loads).
// grid = (CCOLS/512, KSP) = 768 blocks -> 3/CU even. 512 divides the
// wq|wk|wv boundaries (4096, 5120). For wo pass wq=wk=wv=wo.
// x staged transposed in LDS: xs[d][b] -> inner loop = 2 b128 broadcasts.
// ---------------------------------------------------------------------------
__global__ __launch_bounds__(128) void gemv4_kernel(
    const float* __restrict__ x, const float* __restrict__ wq,
    const float* __restrict__ wk, const float* __restrict__ wv,
    float* __restrict__ part, int pstride)
{
    __shared__ float xs[DCH*NB];       // [d][b]
    const int tx = threadIdx.x;
    const int d0 = blockIdx.y*DCH;
    for (int i = tx; i < DCH*NB; i += 128)          // i = b*64 + d
        xs[(i&63)*NB + (i>>6)] = x[(i>>6)*DIM + d0 + (i&63)];
    __syncthreads();

    const int colbase = blockIdx.x*512;
    const float* w; int wcols, wcol;
    if (colbase < QCOLS)               { w = wq; wcols = QCOLS;  wcol = colbase; }
    else if (colbase < QCOLS+KVCOLS)   { w = wk; wcols = KVCOLS; wcol = colbase - QCOLS; }
    else                               { w = wv; wcols = KVCOLS; wcol = colbase - QCOLS - KVCOLS; }

    const float* wp = w + (size_t)d0*wcols + wcol + tx*4;
    float4 a[NB];
    #pragma unroll
    for (int b = 0; b < NB; b++) { a[b].x=0.f; a[b].y=0.f; a[b].z=0.f; a[b].w=0.f; }

    #pragma unroll 4
    for (int dl = 0; dl < DCH; dl++) {
        float4 wv4 = *reinterpret_cast<const float4*>(wp + (size_t)dl*wcols);
        float4 x0 = *reinterpret_cast<const float4*>(&xs[dl*NB]);
        float4 x1 = *reinterpret_cast<const float4*>(&xs[dl*NB + 4]);
        a[0].x += wv4.x*x0.x; a[0].y += wv4.y*x0.x; a[0].z += wv4.z*x0.x; a[0].w += wv4.w*x0.x;
        a[1].x += wv4.x*x0.y; a[1].y += wv4.y*x0.y; a[1].z += wv4.z*x0.y; a[1].w += wv4.w*x0.y;
        a[2].x += wv4.x*x0.z; a[2].y += wv4.y*x0.z; a[2].z += wv4.z*x0.z; a[2].w += wv4.w*x0.z;
        a[3].x += wv4.x*x0.w; a[3].y += wv4.y*x0.w; a[3].z += wv4.z*x0.w; a[3].w += wv4.w*x0.w;
        a[4].x += wv4.x*x1.x; a[4].y += wv4.y*x1.x; a[4].z += wv4.z*x1.x; a[4].w += wv4.w*x1.x;
        a[5].x += wv4.x*x1.y; a[5].y += wv4.y*x1.y; a[5].z += wv4.z*x1.y; a[5].w += wv4.w*x1.y;
        a[6].x += wv4.x*x1.z; a[6].y += wv4.y*x1.z; a[6].z += wv4.z*x1.z; a[6].w += wv4.w*x1.z;
        a[7].x += wv4.x*x1.w; a[7].y += wv4.y*x1.w; a[7].z += wv4.z*x1.w; a[7].w += wv4.w*x1.w;
    }
    const int ocol = colbase + tx*4;
    #pragma unroll
    for (int b = 0; b < NB; b++)
        *reinterpret_cast<float4*>(&part[((size_t)(blockIdx.y*NB + b))*pstride + ocol]) = a[b];
}

// ---------------------------------------------------------------------------
// Reduce QKV split-K partials (float2) + RoPE on q,k.
// ---------------------------------------------------------------------------
__global__ __launch_bounds__(256) void qkv_reduce_rope(
    const float* __restrict__ part, const float* __restrict__ fc,
    const float* __restrict__ fs, float* __restrict__ q,
    float* __restrict__ knew, float* __restrict__ vnew)
{
    const int p = blockIdx.x*256 + threadIdx.x;   // 0 .. NB*CCOLS/2-1
    const int b = p / (CCOLS/2);
    const int c0 = (p % (CCOLS/2))*2;
    float s0 = 0.f, s1 = 0.f;
    const float* pb = part + (size_t)b*CCOLS + c0;
    #pragma unroll 8
    for (int ky = 0; ky < KSP; ky++) {
        float2 v = *reinterpret_cast<const float2*>(pb + (size_t)ky*NB*CCOLS);
        s0 += v.x; s1 += v.y;
    }
    float r0 = s0, r1 = s1;
    if (c0 < QCOLS + KVCOLS) {           // q or k: rope
        int i = (c0 & (HD-1)) >> 1;
        float c = fc[i], s = fs[i];
        r0 = s0*c - s1*s;
        r1 = s0*s + s1*c;
    }
    if (c0 < QCOLS) {
        *reinterpret_cast<float2*>(&q[b*QCOLS + c0]) = make_float2(r0, r1);
    } else if (c0 < QCOLS + KVCOLS) {
        *reinterpret_cast<float2*>(&knew[b*KVCOLS + (c0 - QCOLS)]) = make_float2(r0, r1);
    } else {
        *reinterpret_cast<float2*>(&vnew[b*KVCOLS + (c0 - QCOLS - KVCOLS)]) = make_float2(r0, r1);
    }
}

// ---------------------------------------------------------------------------
// Flash-decode partial, TCH=64. Block = (chunk, kvh, b), 256 threads.
// K staged in LDS (coalesced, XOR-swizzled). Scores in registers; softmax
// partial via 64-lane butterfly. PV: wave j owns rows [16j,16j+16) x ALL 4
// heads, lanes across d (float2, fully unrolled -> 16 loads in flight/lane);
// V tile read exactly once per block; cross-wave combine via LDS partials.
// ---------------------------------------------------------------------------
__global__ __launch_bounds__(256) void attn_part_kernel(
    const float* __restrict__ q, const float* __restrict__ knew,
    const float* __restrict__ vnew, const float* __restrict__ K,
    const float* __restrict__ V, float* __restrict__ pout,
    float* __restrict__ pml)
{
    __shared__ float ks[TCH*HD];    // 32 KB, swizzled
    __shared__ float qs[4*HD];      // 2 KB
    __shared__ float ps[4*TCH];     // 1 KB   [head][row]
    __shared__ float ps2[16*HD];    // 8 KB   [wave*4+head][d]
    const int tx = threadIdx.x;
    const int chunk = blockIdx.x, kvh = blockIdx.y, b = blockIdx.z;
    const int tbase = chunk*TCH;
    const size_t blkid = (size_t)(b*NKVH + kvh)*NCH + chunk;

    {   // q: 512 floats
        int i0 = tx, i1 = tx + 256;
        qs[i0] = q[b*QCOLS + kvh*4*HD + i0];
        qs[i1] = q[b*QCOLS + kvh*4*HD + i1];
    }
    // K staging: 2048 float4s, 8 per thread, coalesced
    const size_t kbase = ((size_t)(b*MAXSEQ + tbase)*NKVH + kvh)*HD;
    #pragma unroll
    for (int k = 0; k < 8; k++) {
        int F = tx + k*256;            // float4 index
        int t = F >> 5, i = F & 31;
        const float4* src;
        if (chunk == NCH-1 && t == TCH-1)
            src = reinterpret_cast<const float4*>(knew + (b*NKVH + kvh)*HD) + i;
        else
            src = reinterpret_cast<const float4*>(K + kbase + (size_t)t*NKVH*HD) + i;
        float4 v = *src;
        int s = i ^ (t & 31);
        *reinterpret_cast<float4*>(&ks[(t*32 + s)*4]) = v;
    }
    __syncthreads();

    const int t = tx & 63, j = tx >> 6;
    // phase 1: score(head j, row t)
    float sj = 0.f;
    {
        const float4* q4 = reinterpret_cast<const float4*>(&qs[j*HD]);
        #pragma unroll 8
        for (int c = 0; c < 32; c++) {
            int s = c ^ (t & 31);
            float4 kv = *reinterpret_cast<const float4*>(&ks[(t*32 + s)*4]);
            float4 qv = q4[c];
            sj += kv.x*qv.x + kv.y*qv.y + kv.z*qv.z + kv.w*qv.w;
        }
        sj *= 0.08838834764831845f;   // 1/sqrt(128)
    }
    // phase 2: wave softmax partial (registers only)
    float m = sj;
    #pragma unroll
    for (int k = 32; k >= 1; k >>= 1) m = fmaxf(m, __shfl_xor(m, k, 64));
    float pw = __expf(sj - m);
    float l = pw;
    #pragma unroll
    for (int k = 32; k >= 1; k >>= 1) l += __shfl_xor(l, k, 64);
    ps[j*TCH + t] = pw;
    if (t == 0) {
        pml[blkid*8 + j] = m;
        pml[blkid*8 + 4 + j] = l;
    }
    __syncthreads();

    // phase 3: PV. wave j -> rows [16j, 16j+16), all 4 heads; lanes = d-pair.
    {
        const int d0 = t*2;
        const int r0 = j*16;
        float a0x=0.f,a0y=0.f, a1x=0.f,a1y=0.f, a2x=0.f,a2y=0.f, a3x=0.f,a3y=0.f;
        const float* vbase = V + ((size_t)(b*MAXSEQ + tbase + r0)*NKVH + kvh)*HD + d0;
        #pragma unroll
        for (int i = 0; i < 16; i++) {
            const float* vp = (chunk == NCH-1 && j == 3 && i == 15)
                ? (vnew + (b*NKVH + kvh)*HD + d0)
                : (vbase + (size_t)i*NKVH*HD);
            float2 vv = *reinterpret_cast<const float2*>(vp);
            float p0 = ps[0*TCH + r0 + i];
            float p1 = ps[1*TCH + r0 + i];
            float p2 = ps[2*TCH + r0 + i];
            float p3 = ps[3*TCH + r0 + i];
            a0x += p0*vv.x; a0y += p0*vv.y;
            a1x += p1*vv.x; a1y += p1*vv.y;
            a2x += p2*vv.x; a2y += p2*vv.y;
            a3x += p3*vv.x; a3y += p3*vv.y;
        }
        *reinterpret_cast<float2*>(&ps2[(j*4 + 0)*HD + d0]) = make_float2(a0x, a0y);
        *reinterpret_cast<float2*>(&ps2[(j*4 + 1)*HD + d0]) = make_float2(a1x, a1y);
        *reinterpret_cast<float2*>(&ps2[(j*4 + 2)*HD + d0]) = make_float2(a2x, a2y);
        *reinterpret_cast<float2*>(&ps2[(j*4 + 3)*HD + d0]) = make_float2(a3x, a3y);
    }
    __syncthreads();

    // cross-wave combine: thread (h = tx>>6, d-pair) sums the 4 wave partials
    {
        const int h = tx >> 6;
        const int d0 = (tx & 63)*2;
        float sx = 0.f, sy = 0.f;
        #pragma unroll
        for (int w = 0; w < 4; w++) {
            float2 v = *reinterpret_cast<const float2*>(&ps2[(w*4 + h)*HD + d0]);
            sx += v.x; sy += v.y;
        }
        *reinterpret_cast<float2*>(pout + blkid*512 + h*HD + d0) = make_float2(sx, sy);
    }
}

// ---------------------------------------------------------------------------
// LSE combine across NCH chunks. Block = (qh, b), 128 threads (d).
// ---------------------------------------------------------------------------
__global__ __launch_bounds__(128) void attn_combine_kernel(
    const float* __restrict__ pout, const float* __restrict__ pml,
    float* __restrict__ attn_out)
{
    const int d = threadIdx.x;
    const int qh = blockIdx.x;
    const int b = blockIdx.y;
    const int kvh = qh >> 2, j = qh & 3;
    const size_t base = (size_t)(b*NKVH + kvh)*NCH;
    float M = -1e30f;
    #pragma unroll 8
    for (int i = 0; i < NCH; i++)
        M = fmaxf(M, pml[(base + i)*8 + j]);
    float L = 0.f, acc = 0.f;
    #pragma unroll 4
    for (int i = 0; i < NCH; i++) {
        float mi = pml[(base + i)*8 + j];
        float wgt = __expf(mi - M);
        L   += wgt * pml[(base + i)*8 + 4 + j];
        acc += wgt * pout[(base + i)*512 + j*HD + d];
    }
    attn_out[b*QCOLS + qh*HD + d] = acc / L;
}

// ---------------------------------------------------------------------------
// Final split-K reduce for wo (float2), f32 output.
// ---------------------------------------------------------------------------
__global__ __launch_bounds__(256) void wo_reduce_kernel(
    const float* __restrict__ part, float* __restrict__ out)
{
    const int g = blockIdx.x*256 + threadIdx.x;   // float2 index, 0..16383
    float sx = 0.f, sy = 0.f;
    #pragma unroll 8
    for (int ky = 0; ky < KSP; ky++) {
        float2 v = *reinterpret_cast<const float2*>(part + (size_t)ky*NB*QCOLS + g*2);
        sx += v.x; sy += v.y;
    }
    *reinterpret_cast<float2*>(out + g*2) = make_float2(sx, sy);
}

extern "C" void kernel_launch(void* const* d_in, const int* in_sizes, int n_in,
                              void* d_out, int out_size, void* d_ws, size_t ws_size,
                              hipStream_t stream)
{
    const float* x  = (const float*)d_in[0];
    // d_in[1] = start_pos (int scalar) = 4095, fixed by the problem.
    const float* fc = (const float*)d_in[2];
    const float* fs = (const float*)d_in[3];
    const float* wq = (const float*)d_in[4];
    const float* wk = (const float*)d_in[5];
    const float* wv = (const float*)d_in[6];
    const float* wo = (const float*)d_in[7];
    const float* K  = (const float*)d_in[8];
    const float* V  = (const float*)d_in[9];

    float* ws     = (float*)d_ws;
    float* q      = ws;                 // 32768
    float* knew   = ws + 32768;         // 8192
    float* vnew   = ws + 40960;         // 8192
    float* attn_o = ws + 49152;         // 32768
    float* A      = ws + 81920;         // shared region, 3,145,728 floats
    // region A time-shared:
    float* qkvp = A;                    // 64*8*6144 = 3,145,728   (k1..k2)
    float* pout = A;                    // 4096*512  = 2,097,152   (k3..k4)
    float* pml  = A + 2097152;          // 4096*8    = 32,768      (k3..k4)
    float* wop  = A;                    // 64*8*4096 = 2,097,152   (k5..k6)
    // total ws use: 81920 + 3,145,728 floats = 12.9 MB

    // 1. fused QKV projection partials (768 blocks = 3/CU even)
    gemv4_kernel<<<dim3(CCOLS/512, KSP), dim3(128), 0, stream>>>(x, wq, wk, wv, qkvp, CCOLS);
    // 2. reduce + RoPE
    qkv_reduce_rope<<<dim3(NB*CCOLS/2/256), dim3(256), 0, stream>>>(qkvp, fc, fs, q, knew, vnew);
    // 3. flash-decode partials
    attn_part_kernel<<<dim3(NCH, NKVH, NB), dim3(256), 0, stream>>>(q, knew, vnew, K, V, pout, pml);
    // 4. LSE combine
    attn_combine_kernel<<<dim3(NQH, NB), dim3(128), 0, stream>>>(pout, pml, attn_o);
    // 5. output projection partials (512 blocks = 2/CU even)
    gemv4_kernel<<<dim3(QCOLS/512, KSP), dim3(128), 0, stream>>>(attn_o, wo, wo, wo, wop, QCOLS);
    // 6. final reduce, f32 out
    wo_reduce_kernel<<<dim3(NB*QCOLS/2/256), dim3(256), 0, stream>>>(wop, (float*)d_out);
}